// Round 9
// baseline (371.385 us; speedup 1.0000x reference)
//
#include <hip/hip_runtime.h>

// Fused GRU-vector-neuron cell, MI355X gfx950 — round 9.
// vs round 8 (245us, latency-bound: no pipe >40%, occupancy 42% @ 2 blocks/CU,
// + spill from rebuild-overlap registers):
//  * r_t evicted from LDS -> r staged through this block's own `out` slice
//    (overwritten by the epilogue after B3; L2-resident, ~0 extra HBM).
//    LDS 58,880 -> 49,984 B -> 3 blocks/CU (75% occupancy ceiling).
//  * rebuild overlap reverted (was spilling 75MB); simple phase order,
//    cross-block overlap at 6 waves/SIMD hides it.
//  * __launch_bounds__(512,6) caps VGPR at 85 (using ~64) for 3 blocks.
// Numerics identical to round 8 (absmax 0.03125): r and K split-bf16 precise,
// delta/z/Q plain; composite weights for delta/Q/K single phase-2.

#define NN   100000
#define NT   16
#define NBLK (NN / NT)   // 6250, exact
#define PSZ  16384       // us per weight plane (128x128 bf16), global ws
#define FS   520         // us per fragment in LDS A-tiles (1040 B)
#define TSZ  (12 * FS)   // us per A-tile (12 frags)
#define GAP  32

typedef unsigned short us;
typedef us     us8    __attribute__((ext_vector_type(8)));
typedef __bf16 bf16x8 __attribute__((ext_vector_type(8)));
typedef float  f32x4  __attribute__((ext_vector_type(4)));

#define MFMA __builtin_amdgcn_mfma_f32_16x16x32_bf16

__device__ __forceinline__ us f2b(float f) {   // RNE, prep only
    union { float f; unsigned u; } x; x.f = f;
    return (us)((x.u + 0x7FFFu + ((x.u >> 16) & 1u)) >> 16);
}
__device__ __forceinline__ float b2f(us h) {
    union { unsigned u; float f; } x; x.u = ((unsigned)h) << 16;
    return x.f;
}

// ---- prep 1: direct weights -> bf16 planes, fragment-major ----
// planes: 0 Whz | 1 Wiz | 2,3 Whr h/l | 4,5 Wir h/l | 6 Whv | 8 Wiv
__global__ void prep_weights(const float* __restrict__ Whz, const float* __restrict__ Wiz,
                             const float* __restrict__ Whr, const float* __restrict__ Wir,
                             const float* __restrict__ Whv, const float* __restrict__ Wiv,
                             us* __restrict__ ws) {
    const int mid = blockIdx.x >> 3;
    const int s = ((blockIdx.x & 7) << 8) + threadIdx.x;
    const float* W; int hp, lp;
    switch (mid) {
        case 0: W = Whz; hp = 0; lp = -1; break;
        case 1: W = Wiz; hp = 1; lp = -1; break;
        case 2: W = Whr; hp = 2; lp = 3;  break;
        case 3: W = Wir; hp = 4; lp = 5;  break;
        case 4: W = Whv; hp = 6; lp = -1; break;
        default: W = Wiv; hp = 8; lp = -1; break;
    }
    const int f = s >> 6, l = s & 63;
    const int o  = (f >> 2) * 16 + (l & 15);
    const int c0 = (f & 3) * 32 + (l >> 4) * 8;
    us8 hi, lo;
#pragma unroll
    for (int j = 0; j < 8; ++j) {
        float x = W[(c0 + j) * 128 + o];
        us h = f2b(x);
        hi[j] = h;
        lo[j] = f2b(x - b2f(h));
    }
    *(us8*)(ws + hp * PSZ + s * 8) = hi;
    if (lp >= 0) *(us8*)(ws + lp * PSZ + s * 8) = lo;
}

// ---- prep 2: composites T = A@B (fp32) -> planes, fragment-major ----
// mat 0: Whv@Wq -> p10 | 1: Wiv@Wq -> p11 | 2: Whv@Wk -> p12,13 | 3: Wiv@Wk -> p14,15
__global__ void prep_comp(const float* __restrict__ Whv, const float* __restrict__ Wiv,
                          const float* __restrict__ Wq,  const float* __restrict__ Wk,
                          us* __restrict__ ws) {
    __shared__ float arow[128];
    const int mat = blockIdx.x >> 7;
    const int c   = blockIdx.x & 127;
    const int o   = threadIdx.x;
    const float* A = (mat & 1) ? Wiv : Whv;
    const float* B = (mat & 2) ? Wk  : Wq;
    arow[o] = A[c * 128 + o];
    __syncthreads();
    float a0 = 0.f, a1 = 0.f, a2 = 0.f, a3 = 0.f;
#pragma unroll 8
    for (int k = 0; k < 128; k += 4) {
        a0 += arow[k + 0] * B[(k + 0) * 128 + o];
        a1 += arow[k + 1] * B[(k + 1) * 128 + o];
        a2 += arow[k + 2] * B[(k + 2) * 128 + o];
        a3 += arow[k + 3] * B[(k + 3) * 128 + o];
    }
    float t = (a0 + a1) + (a2 + a3);
    const int f = (o >> 4) * 4 + (c >> 5);
    const int l = (((c >> 3) & 3) << 4) + (o & 15);
    const int off = (f * 64 + l) * 8 + (c & 7);
    static const int hpt[4] = {10, 11, 12, 14};
    const int hp = hpt[mat];
    us h = f2b(t);
    ws[hp * PSZ + off] = h;
    if (mat & 2) ws[(hp + 1) * PSZ + off] = f2b(t - b2f(h));
}

// ---- load 4 B-fragments (one kf) from planes P0..P3 ----
template <int P0, int P1, int P2, int P3>
__device__ __forceinline__ void loadB4P(const us* __restrict__ ws, int wbk, bf16x8* B) {
    B[0] = *(const bf16x8*)(ws + P0 * PSZ + wbk);
    B[1] = *(const bf16x8*)(ws + P1 * PSZ + wbk);
    B[2] = *(const bf16x8*)(ws + P2 * PSZ + wbk);
    B[3] = *(const bf16x8*)(ws + P3 * PSZ + wbk);
}
// one half-step at kf: A tile (hi,lo) vs B = {Wd_h, CQ, CK_h, CK_l}
// d plain (1), q plain (1), k precise (3)
__device__ __forceinline__ void p2_half(const us* __restrict__ Ah, const us* __restrict__ Al,
                                        const bf16x8* B, int kf, int ab,
                                        f32x4* dacc, f32x4* qacc, f32x4* kacc) {
#pragma unroll
    for (int m = 0; m < 3; ++m) {
        const int fo = (m * 4 + kf) * FS + ab;
        bf16x8 ah = *(const bf16x8*)(Ah + fo);
        bf16x8 al = *(const bf16x8*)(Al + fo);
        dacc[m] = MFMA(ah, B[0], dacc[m], 0, 0, 0);
        qacc[m] = MFMA(ah, B[1], qacc[m], 0, 0, 0);
        kacc[m] = MFMA(ah, B[2], kacc[m], 0, 0, 0);
        kacc[m] = MFMA(al, B[2], kacc[m], 0, 0, 0);
        kacc[m] = MFMA(ah, B[3], kacc[m], 0, 0, 0);
    }
}

__device__ __forceinline__ void loadB4(const us* __restrict__ p, int wb, bf16x8* d) {
#pragma unroll
    for (int kf = 0; kf < 4; ++kf) d[kf] = *(const bf16x8*)(p + wb + kf * 512);
}
// zacc += Ah@Bz (plain); racc += Ah@Bh + Al@Bh + Ah@Bl (precise)
__device__ __forceinline__ void mm_zr(const us* __restrict__ Ah, const us* __restrict__ Al,
                                      const bf16x8* bz, const bf16x8* bh, const bf16x8* bl,
                                      f32x4* zacc, f32x4* racc, int ab) {
#pragma unroll
    for (int kf = 0; kf < 4; ++kf)
#pragma unroll
        for (int m = 0; m < 3; ++m) {
            bf16x8 ah = *(const bf16x8*)(Ah + (m * 4 + kf) * FS + ab);
            bf16x8 al = *(const bf16x8*)(Al + (m * 4 + kf) * FS + ab);
            zacc[m] = MFMA(ah, bz[kf], zacc[m], 0, 0, 0);
            racc[m] = MFMA(ah, bh[kf], racc[m], 0, 0, 0);
            racc[m] = MFMA(al, bh[kf], racc[m], 0, 0, 0);
            racc[m] = MFMA(ah, bl[kf], racc[m], 0, 0, 0);
        }
}

__global__ __launch_bounds__(512, 6) void gru_vn_fused(
    const float* __restrict__ v, const float* __restrict__ mv,
    const float* __restrict__ bz, const float* __restrict__ br,
    const us* __restrict__ ws, float* __restrict__ out)
{
    __shared__ __align__(16) us pool[4 * TSZ + GAP];

    us* const vth = pool;                  // v, later r*v (hi)
    us* const vtl = pool + TSZ;            // v, later r*v (lo)
    us* const mvh = pool + 2 * TSZ + GAP;  // m_v (hi)
    us* const mvl = pool + 3 * TSZ + GAP;  // m_v (lo)

    const int tid  = threadIdx.x;
    const int lane = tid & 63;
    const int wave = tid >> 6;
    const int arow = lane & 15;
    const int bo   = wave * 16 + arow;       // output channel
    const int rsub = (lane >> 4) * 4;        // C-frag row offset
    const int ab   = lane * 8;               // A-frag lane offset (us)
    const int wb   = wave * 2048 + lane * 8; // B-frag base in ws (us)
    const int n0   = blockIdx.x * NT;

    // r staging area: this block's own out slice (overwritten by epilogue)
    float* const rscr = out + (size_t)n0 * 384;   // r[i][c] at rscr[i*384 + c]

    const us* pWhz  = ws;            const us* pWiz  = ws + 1 * PSZ;
    const us* pWhrh = ws + 2 * PSZ;  const us* pWhrl = ws + 3 * PSZ;
    const us* pWirh = ws + 4 * PSZ;  const us* pWirl = ws + 5 * PSZ;

    // ---- stage v, m_v (hi/lo): thread = (node, c8-group, v|mv) ----
    {
        const int which = tid & 1;
        const int c8    = (tid >> 1) & 15;
        const int ind   = tid >> 5;
        const float* src = (which ? mv : v) + (size_t)(n0 + ind) * 384 + c8 * 24;
        float x[24];
#pragma unroll
        for (int t = 0; t < 6; ++t) *(float4*)(x + 4 * t) = *(const float4*)(src + 4 * t);
        us* const dh = which ? mvh : vth;
        us* const dl = which ? mvl : vtl;
        const int f0  = c8 >> 2;
        const int row = ind + ((c8 & 3) << 4);
#pragma unroll
        for (int d = 0; d < 3; ++d) {
            us8 hh, ll;
#pragma unroll
            for (int j = 0; j < 8; ++j) {
                float xv = x[j * 3 + d];
                __bf16 h = (__bf16)xv;
                hh[j] = __builtin_bit_cast(us, h);
                ll[j] = __builtin_bit_cast(us, (__bf16)(xv - (float)h));
            }
            const int off = (d * 4 + f0) * FS + row * 8;
            *(us8*)(dh + off) = hh;
            *(us8*)(dl + off) = ll;
        }
    }
    const float bzv = bz[bo], brv = br[bo];
    const f32x4 Z4 = {0.f, 0.f, 0.f, 0.f};

    bf16x8 Bz[4], Brh[4], Brl[4];
    loadB4(pWhz, wb, Bz); loadB4(pWhrh, wb, Brh); loadB4(pWhrl, wb, Brl);
    __syncthreads();                                   // B1: tiles ready

    // ---- phase 1: z (plain) + r (precise) ----
    f32x4 zacc[3] = {Z4, Z4, Z4}, racc[3] = {Z4, Z4, Z4};
    mm_zr(mvh, mvl, Bz, Brh, Brl, zacc, racc, ab);
    loadB4(pWiz, wb, Bz); loadB4(pWirh, wb, Brh); loadB4(pWirl, wb, Brl);
    mm_zr(vth, vtl, Bz, Brh, Brl, zacc, racc, ab);

    const int vbase = (bo >> 5) * FS + (rsub + (((bo >> 3) & 3) << 4)) * 8 + (bo & 7);
    float zz[4], vout[4][3];
#pragma unroll
    for (int q = 0; q < 4; ++q) {
        float h0 = zacc[0][q], h1 = zacc[1][q], h2 = zacc[2][q];
        zz[q] = 1.f / (1.f + __expf(-(sqrtf(h0 * h0 + h1 * h1 + h2 * h2) + bzv)));
        float r0 = racc[0][q], r1 = racc[1][q], r2 = racc[2][q];
        float rr = 1.f / (1.f + __expf(-(sqrtf(r0 * r0 + r1 * r1 + r2 * r2) + brv)));
        rscr[(rsub + q) * 384 + bo] = rr;              // r -> out-slice scratch
#pragma unroll
        for (int d = 0; d < 3; ++d) {
            int off = vbase + d * 4 * FS + q * 8;
            vout[q][d] = b2f(vth[off]) + b2f(vtl[off]);
        }
    }
    // preload pass-A kf0 B-frags (4 planes)
    bf16x8 BA[4];
    loadB4P<6, 10, 12, 13>(ws, wb, BA);
    __syncthreads();                        // B2: drains r stores; v reads done

    // ---- overwrite v tiles with r*v (hi/lo); r from L1-hot scratch ----
#pragma unroll
    for (int it = 0; it < 2; ++it) {
        int s = tid + it * 512;
        if (s < 768) {                                 // wave-uniform guard
            int f = s >> 6, l = s & 63;
            int i = l & 15, cb = ((f & 3) << 5) + ((l >> 4) << 3);
            int off = f * FS + l * 8;
            us8 vh8 = *(const us8*)(vth + off);
            us8 vl8 = *(const us8*)(vtl + off);
            float4 ra = *(const float4*)(rscr + i * 384 + cb);
            float4 rb = *(const float4*)(rscr + i * 384 + cb + 4);
            float rj[8] = {ra.x, ra.y, ra.z, ra.w, rb.x, rb.y, rb.z, rb.w};
            us8 oh, ol;
#pragma unroll
            for (int j = 0; j < 8; ++j) {
                float p = rj[j] * (b2f(vh8[j]) + b2f(vl8[j]));
                __bf16 h = (__bf16)p;
                oh[j] = __builtin_bit_cast(us, h);
                ol[j] = __builtin_bit_cast(us, (__bf16)(p - (float)h));
            }
            *(us8*)(vth + off) = oh;
            *(us8*)(vtl + off) = ol;
        }
    }

    // ---- phase 2 pass A (mv tiles) — safe before B3 (disjoint tiles) ----
    f32x4 dacc[3] = {Z4, Z4, Z4}, qacc[3] = {Z4, Z4, Z4}, kacc[3] = {Z4, Z4, Z4};
    p2_half(mvh, mvl, BA, 0, ab, dacc, qacc, kacc);
#pragma unroll
    for (int kf = 1; kf < 4; ++kf) {
        bf16x8 B[4];
        loadB4P<6, 10, 12, 13>(ws, wb + kf * 512, B);
        p2_half(mvh, mvl, B, kf, ab, dacc, qacc, kacc);
    }
    __syncthreads();                                   // B3: rv visible

    // ---- phase 2 pass B (rv tiles) ----
#pragma unroll
    for (int kf = 0; kf < 4; ++kf) {
        bf16x8 B[4];
        loadB4P<8, 11, 14, 15>(ws, wb + kf * 512, B);
        p2_half(vth, vtl, B, kf, ab, dacc, qacc, kacc);
    }

    // ---- vn-leaky + gate + store (overwrites r scratch region) ----
#pragma unroll
    for (int q = 0; q < 4; ++q) {
        const int i = rsub + q;
        float q0 = qacc[0][q], q1 = qacc[1][q], q2 = qacc[2][q];
        float k0 = kacc[0][q], k1 = kacc[1][q], k2 = kacc[2][q];
        float inner = fminf(q0 * k0 + q1 * k1 + q2 * k2, 0.f);
        float kn = sqrtf(k0 * k0 + k1 * k1 + k2 * k2) + 1e-7f;
        float s = inner / (kn * kn);
        float z = zz[q];
        float dv0 = 0.3f * dacc[0][q] + 0.7f * (q0 - s * k0);
        float dv1 = 0.3f * dacc[1][q] + 0.7f * (q1 - s * k1);
        float dv2 = 0.3f * dacc[2][q] + 0.7f * (q2 - s * k2);
        float* op = out + ((size_t)(n0 + i) * 128 + bo) * 3;
        op[0] = (1.f - z) * vout[q][0] + z * dv0;
        op[1] = (1.f - z) * vout[q][1] + z * dv1;
        op[2] = (1.f - z) * vout[q][2] + z * dv2;
    }
}

extern "C" void kernel_launch(void* const* d_in, const int* in_sizes, int n_in,
                              void* d_out, int out_size, void* d_ws, size_t ws_size,
                              hipStream_t stream) {
    (void)in_sizes; (void)n_in; (void)ws_size; (void)out_size;
    us* ws = (us*)d_ws;
    prep_weights<<<48, 256, 0, stream>>>(
        (const float*)d_in[2], (const float*)d_in[3],
        (const float*)d_in[5], (const float*)d_in[6],
        (const float*)d_in[8], (const float*)d_in[9], ws);
    prep_comp<<<512, 128, 0, stream>>>(
        (const float*)d_in[8],  (const float*)d_in[9],
        (const float*)d_in[10], (const float*)d_in[11], ws);
    gru_vn_fused<<<NBLK, 512, 0, stream>>>(
        (const float*)d_in[0], (const float*)d_in[1],
        (const float*)d_in[4], (const float*)d_in[7],
        ws, (float*)d_out);
}

// Round 10
// 242.508 us; speedup vs baseline: 1.5314x; 1.5314x over previous
//
#include <hip/hip_runtime.h>

// Fused GRU-vector-neuron cell, MI355X gfx950 — round 10.
// vs round 9 (371us REGRESSION: out-as-scratch caused 600MB extra HBM traffic
// + VGPR squeeze; occupancy rose to 64% yet time got worse -> NOT occupancy
// bound). Revert to the R8 shape and remove its two defects:
//  * r_t back in LDS [c*17+i] (58.9KB, 2 blk/CU) — no global r round-trip.
//  * rebuild is a simple pass (no operands held across MFMA -> no spill).
//  * phase-2 B-frag loads software-pipelined one kf ahead (B[2][4] regs,
//    static idx): hides the ~200-500cy L2 latency that was serially exposed
//    at every kf iteration. passB kf0 prefetched during passA kf3.
// Numerics identical (absmax 0.03125): r and K split-bf16 precise (3 MFMAs),
// delta/z/Q plain; composite weights Q=mv@(Whv·Wq)+rv@(Wiv·Wq), K likewise.

#define NN   100000
#define NT   16
#define NBLK (NN / NT)   // 6250, exact
#define PSZ  16384       // us per weight plane (128x128 bf16), global ws
#define FS   520         // us per fragment in LDS A-tiles (1040 B)
#define TSZ  (12 * FS)   // us per A-tile (12 frags)
#define GAP  32

typedef unsigned short us;
typedef us     us8    __attribute__((ext_vector_type(8)));
typedef __bf16 bf16x8 __attribute__((ext_vector_type(8)));
typedef float  f32x4  __attribute__((ext_vector_type(4)));

#define MFMA __builtin_amdgcn_mfma_f32_16x16x32_bf16

__device__ __forceinline__ us f2b(float f) {   // RNE, prep only
    union { float f; unsigned u; } x; x.f = f;
    return (us)((x.u + 0x7FFFu + ((x.u >> 16) & 1u)) >> 16);
}
__device__ __forceinline__ float b2f(us h) {
    union { unsigned u; float f; } x; x.u = ((unsigned)h) << 16;
    return x.f;
}

// ---- prep 1: direct weights -> bf16 planes, fragment-major ----
// planes: 0 Whz | 1 Wiz | 2,3 Whr h/l | 4,5 Wir h/l | 6 Whv | 8 Wiv
__global__ void prep_weights(const float* __restrict__ Whz, const float* __restrict__ Wiz,
                             const float* __restrict__ Whr, const float* __restrict__ Wir,
                             const float* __restrict__ Whv, const float* __restrict__ Wiv,
                             us* __restrict__ ws) {
    const int mid = blockIdx.x >> 3;
    const int s = ((blockIdx.x & 7) << 8) + threadIdx.x;
    const float* W; int hp, lp;
    switch (mid) {
        case 0: W = Whz; hp = 0; lp = -1; break;
        case 1: W = Wiz; hp = 1; lp = -1; break;
        case 2: W = Whr; hp = 2; lp = 3;  break;
        case 3: W = Wir; hp = 4; lp = 5;  break;
        case 4: W = Whv; hp = 6; lp = -1; break;
        default: W = Wiv; hp = 8; lp = -1; break;
    }
    const int f = s >> 6, l = s & 63;
    const int o  = (f >> 2) * 16 + (l & 15);
    const int c0 = (f & 3) * 32 + (l >> 4) * 8;
    us8 hi, lo;
#pragma unroll
    for (int j = 0; j < 8; ++j) {
        float x = W[(c0 + j) * 128 + o];
        us h = f2b(x);
        hi[j] = h;
        lo[j] = f2b(x - b2f(h));
    }
    *(us8*)(ws + hp * PSZ + s * 8) = hi;
    if (lp >= 0) *(us8*)(ws + lp * PSZ + s * 8) = lo;
}

// ---- prep 2: composites T = A@B (fp32) -> planes, fragment-major ----
// mat 0: Whv@Wq -> p10 | 1: Wiv@Wq -> p11 | 2: Whv@Wk -> p12,13 | 3: Wiv@Wk -> p14,15
__global__ void prep_comp(const float* __restrict__ Whv, const float* __restrict__ Wiv,
                          const float* __restrict__ Wq,  const float* __restrict__ Wk,
                          us* __restrict__ ws) {
    __shared__ float arow[128];
    const int mat = blockIdx.x >> 7;
    const int c   = blockIdx.x & 127;
    const int o   = threadIdx.x;
    const float* A = (mat & 1) ? Wiv : Whv;
    const float* B = (mat & 2) ? Wk  : Wq;
    arow[o] = A[c * 128 + o];
    __syncthreads();
    float a0 = 0.f, a1 = 0.f, a2 = 0.f, a3 = 0.f;
#pragma unroll 8
    for (int k = 0; k < 128; k += 4) {
        a0 += arow[k + 0] * B[(k + 0) * 128 + o];
        a1 += arow[k + 1] * B[(k + 1) * 128 + o];
        a2 += arow[k + 2] * B[(k + 2) * 128 + o];
        a3 += arow[k + 3] * B[(k + 3) * 128 + o];
    }
    float t = (a0 + a1) + (a2 + a3);
    const int f = (o >> 4) * 4 + (c >> 5);
    const int l = (((c >> 3) & 3) << 4) + (o & 15);
    const int off = (f * 64 + l) * 8 + (c & 7);
    static const int hpt[4] = {10, 11, 12, 14};
    const int hp = hpt[mat];
    us h = f2b(t);
    ws[hp * PSZ + off] = h;
    if (mat & 2) ws[(hp + 1) * PSZ + off] = f2b(t - b2f(h));
}

// ---- load 4 B-fragments (one kf) from planes P0..P3 ----
template <int P0, int P1, int P2, int P3>
__device__ __forceinline__ void loadB4P(const us* __restrict__ ws, int wbk, bf16x8* B) {
    B[0] = *(const bf16x8*)(ws + P0 * PSZ + wbk);
    B[1] = *(const bf16x8*)(ws + P1 * PSZ + wbk);
    B[2] = *(const bf16x8*)(ws + P2 * PSZ + wbk);
    B[3] = *(const bf16x8*)(ws + P3 * PSZ + wbk);
}
// one half-step at kf: A tile (hi,lo) vs B = {Wd_h, CQ, CK_h, CK_l}
// d plain (1), q plain (1), k precise (3)
__device__ __forceinline__ void p2_half(const us* __restrict__ Ah, const us* __restrict__ Al,
                                        const bf16x8* B, int kf, int ab,
                                        f32x4* dacc, f32x4* qacc, f32x4* kacc) {
#pragma unroll
    for (int m = 0; m < 3; ++m) {
        const int fo = (m * 4 + kf) * FS + ab;
        bf16x8 ah = *(const bf16x8*)(Ah + fo);
        bf16x8 al = *(const bf16x8*)(Al + fo);
        dacc[m] = MFMA(ah, B[0], dacc[m], 0, 0, 0);
        qacc[m] = MFMA(ah, B[1], qacc[m], 0, 0, 0);
        kacc[m] = MFMA(ah, B[2], kacc[m], 0, 0, 0);
        kacc[m] = MFMA(al, B[2], kacc[m], 0, 0, 0);
        kacc[m] = MFMA(ah, B[3], kacc[m], 0, 0, 0);
    }
}

__device__ __forceinline__ void loadB4(const us* __restrict__ p, int wb, bf16x8* d) {
#pragma unroll
    for (int kf = 0; kf < 4; ++kf) d[kf] = *(const bf16x8*)(p + wb + kf * 512);
}
// zacc += Ah@Bz (plain); racc += Ah@Bh + Al@Bh + Ah@Bl (precise)
__device__ __forceinline__ void mm_zr(const us* __restrict__ Ah, const us* __restrict__ Al,
                                      const bf16x8* bz, const bf16x8* bh, const bf16x8* bl,
                                      f32x4* zacc, f32x4* racc, int ab) {
#pragma unroll
    for (int kf = 0; kf < 4; ++kf)
#pragma unroll
        for (int m = 0; m < 3; ++m) {
            bf16x8 ah = *(const bf16x8*)(Ah + (m * 4 + kf) * FS + ab);
            bf16x8 al = *(const bf16x8*)(Al + (m * 4 + kf) * FS + ab);
            zacc[m] = MFMA(ah, bz[kf], zacc[m], 0, 0, 0);
            racc[m] = MFMA(ah, bh[kf], racc[m], 0, 0, 0);
            racc[m] = MFMA(al, bh[kf], racc[m], 0, 0, 0);
            racc[m] = MFMA(ah, bl[kf], racc[m], 0, 0, 0);
        }
}

__global__ __launch_bounds__(512, 4) void gru_vn_fused(
    const float* __restrict__ v, const float* __restrict__ mv,
    const float* __restrict__ bz, const float* __restrict__ br,
    const us* __restrict__ ws, float* __restrict__ out)
{
    __shared__ __align__(16) us pool[4 * TSZ + GAP];
    __shared__ __align__(16) float r_t[128 * 17];       // r fp32, [c*17 + i]

    us* const vth = pool;                  // v, later r*v (hi)
    us* const vtl = pool + TSZ;            // v, later r*v (lo)
    us* const mvh = pool + 2 * TSZ + GAP;  // m_v (hi)
    us* const mvl = pool + 3 * TSZ + GAP;  // m_v (lo)

    const int tid  = threadIdx.x;
    const int lane = tid & 63;
    const int wave = tid >> 6;
    const int arow = lane & 15;
    const int bo   = wave * 16 + arow;       // output channel
    const int rsub = (lane >> 4) * 4;        // C-frag row offset
    const int ab   = lane * 8;               // A-frag lane offset (us)
    const int wb   = wave * 2048 + lane * 8; // B-frag base in ws (us)
    const int n0   = blockIdx.x * NT;

    const us* pWhz  = ws;            const us* pWiz  = ws + 1 * PSZ;
    const us* pWhrh = ws + 2 * PSZ;  const us* pWhrl = ws + 3 * PSZ;
    const us* pWirh = ws + 4 * PSZ;  const us* pWirl = ws + 5 * PSZ;

    // ---- stage v, m_v (hi/lo): thread = (node, c8-group, v|mv) ----
    {
        const int which = tid & 1;
        const int c8    = (tid >> 1) & 15;
        const int ind   = tid >> 5;
        const float* src = (which ? mv : v) + (size_t)(n0 + ind) * 384 + c8 * 24;
        float x[24];
#pragma unroll
        for (int t = 0; t < 6; ++t) *(float4*)(x + 4 * t) = *(const float4*)(src + 4 * t);
        us* const dh = which ? mvh : vth;
        us* const dl = which ? mvl : vtl;
        const int f0  = c8 >> 2;
        const int row = ind + ((c8 & 3) << 4);
#pragma unroll
        for (int d = 0; d < 3; ++d) {
            us8 hh, ll;
#pragma unroll
            for (int j = 0; j < 8; ++j) {
                float xv = x[j * 3 + d];
                __bf16 h = (__bf16)xv;
                hh[j] = __builtin_bit_cast(us, h);
                ll[j] = __builtin_bit_cast(us, (__bf16)(xv - (float)h));
            }
            const int off = (d * 4 + f0) * FS + row * 8;
            *(us8*)(dh + off) = hh;
            *(us8*)(dl + off) = ll;
        }
    }
    const float bzv = bz[bo], brv = br[bo];
    const f32x4 Z4 = {0.f, 0.f, 0.f, 0.f};

    bf16x8 Bz[4], Brh[4], Brl[4];
    loadB4(pWhz, wb, Bz); loadB4(pWhrh, wb, Brh); loadB4(pWhrl, wb, Brl);
    __syncthreads();                                   // B1: tiles ready

    // ---- phase 1: z (plain) + r (precise) ----
    f32x4 zacc[3] = {Z4, Z4, Z4}, racc[3] = {Z4, Z4, Z4};
    mm_zr(mvh, mvl, Bz, Brh, Brl, zacc, racc, ab);
    loadB4(pWiz, wb, Bz); loadB4(pWirh, wb, Brh); loadB4(pWirl, wb, Brl);
    mm_zr(vth, vtl, Bz, Brh, Brl, zacc, racc, ab);

    const int vbase = (bo >> 5) * FS + (rsub + (((bo >> 3) & 3) << 4)) * 8 + (bo & 7);
    float zz[4], vout[4][3];
#pragma unroll
    for (int q = 0; q < 4; ++q) {
        float h0 = zacc[0][q], h1 = zacc[1][q], h2 = zacc[2][q];
        zz[q] = 1.f / (1.f + __expf(-(sqrtf(h0 * h0 + h1 * h1 + h2 * h2) + bzv)));
        float r0 = racc[0][q], r1 = racc[1][q], r2 = racc[2][q];
        float rr = 1.f / (1.f + __expf(-(sqrtf(r0 * r0 + r1 * r1 + r2 * r2) + brv)));
        r_t[bo * 17 + rsub + q] = rr;
#pragma unroll
        for (int d = 0; d < 3; ++d) {
            int off = vbase + d * 4 * FS + q * 8;
            vout[q][d] = b2f(vth[off]) + b2f(vtl[off]);
        }
    }
    // pipeline: pass-A kf0 B-frags in flight across the barrier
    bf16x8 B[2][4];
    loadB4P<6, 10, 12, 13>(ws, wb, B[0]);
    __syncthreads();                                   // B2: r_t visible; v reads done

    // ---- overwrite v tiles with r*v (hi/lo), simple pass ----
#pragma unroll
    for (int it = 0; it < 2; ++it) {
        int s = tid + it * 512;
        if (s < 768) {                                 // wave-uniform guard
            int f = s >> 6, l = s & 63;
            int i = l & 15, cb = ((f & 3) << 5) + ((l >> 4) << 3);
            int off = f * FS + l * 8;
            us8 vh8 = *(const us8*)(vth + off);
            us8 vl8 = *(const us8*)(vtl + off);
            us8 oh, ol;
#pragma unroll
            for (int j = 0; j < 8; ++j) {
                float p = r_t[(cb + j) * 17 + i] * (b2f(vh8[j]) + b2f(vl8[j]));
                __bf16 h = (__bf16)p;
                oh[j] = __builtin_bit_cast(us, h);
                ol[j] = __builtin_bit_cast(us, (__bf16)(p - (float)h));
            }
            *(us8*)(vth + off) = oh;
            *(us8*)(vtl + off) = ol;
        }
    }

    // ---- phase 2 pass A (mv tiles), one-kf-ahead pipelined ----
    f32x4 dacc[3] = {Z4, Z4, Z4}, qacc[3] = {Z4, Z4, Z4}, kacc[3] = {Z4, Z4, Z4};
#pragma unroll
    for (int kf = 0; kf < 4; ++kf) {
        const int cur = kf & 1, nxt = cur ^ 1;
        if (kf < 3) loadB4P<6, 10, 12, 13>(ws, wb + (kf + 1) * 512, B[nxt]);
        else        loadB4P<8, 11, 14, 15>(ws, wb, B[nxt]);  // pass-B kf0
        p2_half(mvh, mvl, B[cur], kf, ab, dacc, qacc, kacc);
    }
    __syncthreads();                                   // B3: rv visible

    // ---- phase 2 pass B (rv tiles), pipelined (kf0 already in B[0]) ----
#pragma unroll
    for (int kf = 0; kf < 4; ++kf) {
        const int cur = kf & 1, nxt = cur ^ 1;
        if (kf < 3) loadB4P<8, 11, 14, 15>(ws, wb + (kf + 1) * 512, B[nxt]);
        p2_half(vth, vtl, B[cur], kf, ab, dacc, qacc, kacc);
    }

    // ---- vn-leaky + gate + store ----
#pragma unroll
    for (int q = 0; q < 4; ++q) {
        const int i = rsub + q;
        float q0 = qacc[0][q], q1 = qacc[1][q], q2 = qacc[2][q];
        float k0 = kacc[0][q], k1 = kacc[1][q], k2 = kacc[2][q];
        float inner = fminf(q0 * k0 + q1 * k1 + q2 * k2, 0.f);
        float kn = sqrtf(k0 * k0 + k1 * k1 + k2 * k2) + 1e-7f;
        float s = inner / (kn * kn);
        float z = zz[q];
        float dv0 = 0.3f * dacc[0][q] + 0.7f * (q0 - s * k0);
        float dv1 = 0.3f * dacc[1][q] + 0.7f * (q1 - s * k1);
        float dv2 = 0.3f * dacc[2][q] + 0.7f * (q2 - s * k2);
        float* op = out + ((size_t)(n0 + i) * 128 + bo) * 3;
        op[0] = (1.f - z) * vout[q][0] + z * dv0;
        op[1] = (1.f - z) * vout[q][1] + z * dv1;
        op[2] = (1.f - z) * vout[q][2] + z * dv2;
    }
}

extern "C" void kernel_launch(void* const* d_in, const int* in_sizes, int n_in,
                              void* d_out, int out_size, void* d_ws, size_t ws_size,
                              hipStream_t stream) {
    (void)in_sizes; (void)n_in; (void)ws_size; (void)out_size;
    us* ws = (us*)d_ws;
    prep_weights<<<48, 256, 0, stream>>>(
        (const float*)d_in[2], (const float*)d_in[3],
        (const float*)d_in[5], (const float*)d_in[6],
        (const float*)d_in[8], (const float*)d_in[9], ws);
    prep_comp<<<512, 128, 0, stream>>>(
        (const float*)d_in[8],  (const float*)d_in[9],
        (const float*)d_in[10], (const float*)d_in[11], ws);
    gru_vn_fused<<<NBLK, 512, 0, stream>>>(
        (const float*)d_in[0], (const float*)d_in[1],
        (const float*)d_in[4], (const float*)d_in[7],
        ws, (float*)d_out);
}